// Round 4
// baseline (486.321 us; speedup 1.0000x reference)
//
#include <hip/hip_runtime.h>
#include <math.h>

#define FIN 512
#define FH 128
#define FOUT 40
#define FP 64   // padded H2 width

typedef __attribute__((ext_vector_type(8))) short bf16x8;
typedef __attribute__((ext_vector_type(4))) float f32x4;

__device__ inline ushort f2bf(float f){
  union { float f; uint32_t u; } v; v.f = f;
  uint32_t u = v.u;
  uint32_t r = (u + 0x7FFF + ((u >> 16) & 1)) >> 16;
  return (ushort)r;
}
__device__ inline float bflo(uint32_t v){ union { uint32_t u; float f; } x; x.u = v << 16; return x.f; }
__device__ inline float bfhi(uint32_t v){ union { uint32_t u; float f; } x; x.u = v & 0xFFFF0000u; return x.f; }
__device__ inline uint32_t pk(float a, float b){ return (uint32_t)f2bf(a) | ((uint32_t)f2bf(b) << 16); }

// ---------------- CSR build ----------------

__global__ void k_zero_int(int* __restrict__ p, int n){
  int i = blockIdx.x*256 + threadIdx.x;
  if(i<n) p[i]=0;
}

__global__ void k_count(const int* __restrict__ dst, int e, int* __restrict__ cnt){
  int i = blockIdx.x*256 + threadIdx.x;
  if(i<e) atomicAdd(&cnt[dst[i]],1);
}

__global__ void k_scan_a(const int* __restrict__ cnt, int n, int* __restrict__ rp, int* __restrict__ aux){
  __shared__ int sh[256];
  int t = threadIdx.x;
  int base = blockIdx.x*1024;
  int v[4]; int s = 0;
  #pragma unroll
  for(int j=0;j<4;j++){ int idx = base + t*4 + j; int x = (idx<n)?cnt[idx]:0; v[j]=x; s+=x; }
  sh[t]=s; __syncthreads();
  for(int off=1; off<256; off<<=1){
    int x = (t>=off)? sh[t-off]:0; __syncthreads();
    sh[t]+=x; __syncthreads();
  }
  int run = (t>0)? sh[t-1]:0;
  #pragma unroll
  for(int j=0;j<4;j++){ run += v[j]; int idx = base + t*4 + j; if(idx<n) rp[idx+1]=run; }
  if(t==255) aux[blockIdx.x]=sh[255];
}

__global__ void k_scan_b(int* __restrict__ aux, int nchunks){
  __shared__ int sh[256];
  int t = threadIdx.x;
  sh[t] = (t<nchunks)? aux[t] : 0;
  __syncthreads();
  for(int off=1; off<256; off<<=1){
    int x = (t>=off)? sh[t-off]:0; __syncthreads();
    sh[t]+=x; __syncthreads();
  }
  if(t<nchunks) aux[t] = (t>0)? sh[t-1] : 0;
}

__global__ void k_scan_c(int* __restrict__ rp, const int* __restrict__ aux,
                         const int* __restrict__ cnt, float* __restrict__ dinv, int n){
  int i = blockIdx.x*256 + threadIdx.x;
  if(i<n){
    rp[i+1] += aux[i>>10];
    dinv[i] = rsqrtf((float)(cnt[i]+1));
  }
  if(i==0) rp[0] = 0;
}

__global__ void k_fill(const int* __restrict__ src, const int* __restrict__ dst, int e,
                       const int* __restrict__ rp, int* __restrict__ cursor, int* __restrict__ srcs){
  int i = blockIdx.x*256 + threadIdx.x;
  if(i<e){
    int d = dst[i];
    int p = rp[d] + atomicAdd(&cursor[d],1);
    srcs[p] = src[i];
  }
}

// ---------------- weight prep: W1 -> bf16 W1t[128][512]; W2 -> bf16 W2t[48][128] (pad 0) ---
__global__ void k_prep(const float* __restrict__ W1, const float* __restrict__ W2,
                       ushort* __restrict__ W1t, ushort* __restrict__ W2t){
  int i = blockIdx.x*256 + threadIdx.x;
  if(i < FIN*FH){
    int k = i / FH, c = i % FH;
    W1t[(size_t)c*FIN + k] = f2bf(W1[i]);
  }
  if(i < 48*FH){
    int c = i / FH, k = i % FH;
    W2t[i] = (c < FOUT) ? f2bf(W2[(size_t)k*FOUT + c]) : (ushort)0;
  }
}

// ---------------- GEMM1 via MFMA: XWs[n,128] = (bf16(X) @ bf16(W1)) * dinv[row] ----------------
// 64 rows/block, wave = 16 rows x 128 cols (acc[8] f32x4) -> 1563 blocks, high wave count.
__global__ __launch_bounds__(256) void k_gemm1_mfma(const float* __restrict__ X,
                                                    const ushort* __restrict__ W1t,
                                                    const float* __restrict__ dinv,
                                                    ushort* __restrict__ XWs, int n){
  int t = threadIdx.x;
  int lane = t & 63;
  int wid = t >> 6;
  int l15 = lane & 15;
  int lk8 = (lane >> 4) * 8;
  int rowbase = blockIdx.x * 64 + wid * 16;

  int r0 = rowbase + l15; if (r0 >= n) r0 = n-1;
  const float* ap = X + (size_t)r0*FIN + lk8;

  f32x4 acc[8];
  #pragma unroll
  for(int j=0;j<8;j++) acc[j] = (f32x4){0.f,0.f,0.f,0.f};

  #pragma unroll 4
  for(int kc=0; kc<16; kc++){
    int k0 = kc*32;
    float4 aa = *(const float4*)(ap + k0);
    float4 ab = *(const float4*)(ap + k0 + 4);
    bf16x8 fa;
    fa[0]=(short)f2bf(aa.x); fa[1]=(short)f2bf(aa.y); fa[2]=(short)f2bf(aa.z); fa[3]=(short)f2bf(aa.w);
    fa[4]=(short)f2bf(ab.x); fa[5]=(short)f2bf(ab.y); fa[6]=(short)f2bf(ab.z); fa[7]=(short)f2bf(ab.w);
    #pragma unroll
    for(int fj=0; fj<8; fj++){
      bf16x8 fb = *(const bf16x8*)(W1t + (size_t)(fj*16 + l15)*FIN + k0 + lk8);
      acc[fj] = __builtin_amdgcn_mfma_f32_16x16x32_bf16(fa, fb, acc[fj], 0, 0, 0);
    }
  }

  int rbase = (lane >> 4) * 4;
  #pragma unroll
  for(int r=0; r<4; r++){
    int row = rowbase + rbase + r;
    if(row < n){
      float dd = dinv[row];
      #pragma unroll
      for(int fj=0; fj<8; fj++){
        XWs[(size_t)row*FH + fj*16 + l15] = f2bf(acc[fj][r] * dd);
      }
    }
  }
}

// ---------------- agg1: H1b = relu(dd*(sum_s XWs[s] + XWs[d]) + b1), bf16 out ----------------
// wave per node; 8 groups x 8 lanes; each group gathers a different edge row (2 x uint4 / lane).
__global__ __launch_bounds__(256) void k_agg1(const ushort* __restrict__ XWs, const int* __restrict__ rp,
                                              const int* __restrict__ srcs, const float* __restrict__ dinv,
                                              const float* __restrict__ b1, ushort* __restrict__ H1b, int n){
  int d = blockIdx.x*4 + (threadIdx.x >> 6);
  if(d >= n) return;
  int lane = threadIdx.x & 63;
  int g = lane >> 3, li = lane & 7;
  float acc[16];
  #pragma unroll
  for(int k=0;k<16;k++) acc[k]=0.f;
  int beg = rp[d], end = rp[d+1];
  for(int j = beg + g; j < end; j += 8){
    int s = srcs[j];
    const uint4* p = (const uint4*)(XWs + (size_t)s*FH + li*16);
    uint4 v0 = p[0];
    uint4 v1 = p[1];
    acc[0]+=bflo(v0.x); acc[1]+=bfhi(v0.x); acc[2]+=bflo(v0.y); acc[3]+=bfhi(v0.y);
    acc[4]+=bflo(v0.z); acc[5]+=bfhi(v0.z); acc[6]+=bflo(v0.w); acc[7]+=bfhi(v0.w);
    acc[8]+=bflo(v1.x); acc[9]+=bfhi(v1.x); acc[10]+=bflo(v1.y); acc[11]+=bfhi(v1.y);
    acc[12]+=bflo(v1.z); acc[13]+=bfhi(v1.z); acc[14]+=bflo(v1.w); acc[15]+=bfhi(v1.w);
  }
  #pragma unroll
  for(int k=0;k<16;k++){
    acc[k] += __shfl_xor(acc[k], 8);
    acc[k] += __shfl_xor(acc[k], 16);
    acc[k] += __shfl_xor(acc[k], 32);
  }
  // self + epilogue
  const uint4* sp = (const uint4*)(XWs + (size_t)d*FH + li*16);
  uint4 s0 = sp[0];
  uint4 s1 = sp[1];
  float dd = dinv[d];
  float slf[16];
  slf[0]=bflo(s0.x); slf[1]=bfhi(s0.x); slf[2]=bflo(s0.y); slf[3]=bfhi(s0.y);
  slf[4]=bflo(s0.z); slf[5]=bfhi(s0.z); slf[6]=bflo(s0.w); slf[7]=bfhi(s0.w);
  slf[8]=bflo(s1.x); slf[9]=bfhi(s1.x); slf[10]=bflo(s1.y); slf[11]=bfhi(s1.y);
  slf[12]=bflo(s1.z); slf[13]=bfhi(s1.z); slf[14]=bflo(s1.w); slf[15]=bfhi(s1.w);
  float o[16];
  #pragma unroll
  for(int k=0;k<16;k++){
    float bb = b1[li*16 + k];
    o[k] = fmaxf((acc[k]+slf[k])*dd + bb, 0.f);
  }
  if(g == 0){
    uint4 w0, w1;
    w0.x = pk(o[0],o[1]);  w0.y = pk(o[2],o[3]);  w0.z = pk(o[4],o[5]);  w0.w = pk(o[6],o[7]);
    w1.x = pk(o[8],o[9]);  w1.y = pk(o[10],o[11]); w1.z = pk(o[12],o[13]); w1.w = pk(o[14],o[15]);
    uint4* wp = (uint4*)(H1b + (size_t)d*FH + li*16);
    wp[0] = w0;
    wp[1] = w1;
  }
}

// ---------------- GEMM2 via MFMA: H2s[n,64] = (H1b @ W2) * dinv[row], bf16, cols>=40 zero ---
__global__ __launch_bounds__(256) void k_gemm2_mfma(const ushort* __restrict__ H1b,
                                                    const ushort* __restrict__ W2t,
                                                    const float* __restrict__ dinv,
                                                    ushort* __restrict__ H2s, int n){
  int t = threadIdx.x;
  int lane = t & 63;
  int wid = t >> 6;
  int l15 = lane & 15;
  int lk8 = (lane >> 4) * 8;
  int rowbase = blockIdx.x * 128 + wid * 32;

  int r0 = rowbase + l15;      if (r0 >= n) r0 = n-1;
  int r1 = rowbase + 16 + l15; if (r1 >= n) r1 = n-1;
  const ushort* a0p = H1b + (size_t)r0*FH + lk8;
  const ushort* a1p = H1b + (size_t)r1*FH + lk8;

  f32x4 acc[2][3];
  #pragma unroll
  for(int i=0;i<2;i++)
    #pragma unroll
    for(int j=0;j<3;j++) acc[i][j] = (f32x4){0.f,0.f,0.f,0.f};

  #pragma unroll
  for(int kc=0; kc<4; kc++){
    int k0 = kc*32;
    bf16x8 fa0 = *(const bf16x8*)(a0p + k0);
    bf16x8 fa1 = *(const bf16x8*)(a1p + k0);
    #pragma unroll
    for(int fj=0; fj<3; fj++){
      bf16x8 fb = *(const bf16x8*)(W2t + (size_t)(fj*16 + l15)*FH + k0 + lk8);
      acc[0][fj] = __builtin_amdgcn_mfma_f32_16x16x32_bf16(fa0, fb, acc[0][fj], 0, 0, 0);
      acc[1][fj] = __builtin_amdgcn_mfma_f32_16x16x32_bf16(fa1, fb, acc[1][fj], 0, 0, 0);
    }
  }

  int rbase = (lane >> 4) * 4;
  #pragma unroll
  for(int fi=0; fi<2; fi++){
    #pragma unroll
    for(int r=0; r<4; r++){
      int row = rowbase + fi*16 + rbase + r;
      if(row < n){
        float dd = dinv[row];
        #pragma unroll
        for(int fj=0; fj<3; fj++){
          int col = fj*16 + l15;
          H2s[(size_t)row*FP + col] = (col < FOUT) ? f2bf(acc[fi][fj][r] * dd) : (ushort)0;
        }
        H2s[(size_t)row*FP + 48 + l15] = 0;
      }
    }
  }
}

// ---------------- agg2 + bias + log_softmax: out[d] = lsm(dd*(sum H2s[s] + H2s[d]) + b2) ---
// wave per node; 8 groups x 8 lanes; 1 uint4/lane covers the 128B padded row.
__global__ __launch_bounds__(256) void k_agg2_sm(const ushort* __restrict__ H2s, const int* __restrict__ rp,
                                                 const int* __restrict__ srcs, const float* __restrict__ dinv,
                                                 const float* __restrict__ b2, float* __restrict__ out, int n){
  int d = blockIdx.x*4 + (threadIdx.x >> 6);
  if(d >= n) return;
  int lane = threadIdx.x & 63;
  int g = lane >> 3, li = lane & 7;
  float acc[8];
  #pragma unroll
  for(int k=0;k<8;k++) acc[k]=0.f;
  int beg = rp[d], end = rp[d+1];
  for(int j = beg + g; j < end; j += 8){
    int s = srcs[j];
    uint4 v = *(const uint4*)(H2s + (size_t)s*FP + li*8);
    acc[0]+=bflo(v.x); acc[1]+=bfhi(v.x); acc[2]+=bflo(v.y); acc[3]+=bfhi(v.y);
    acc[4]+=bflo(v.z); acc[5]+=bfhi(v.z); acc[6]+=bflo(v.w); acc[7]+=bfhi(v.w);
  }
  #pragma unroll
  for(int k=0;k<8;k++){
    acc[k] += __shfl_xor(acc[k], 8);
    acc[k] += __shfl_xor(acc[k], 16);
    acc[k] += __shfl_xor(acc[k], 32);
  }
  uint4 sv = *(const uint4*)(H2s + (size_t)d*FP + li*8);
  acc[0]+=bflo(sv.x); acc[1]+=bfhi(sv.x); acc[2]+=bflo(sv.y); acc[3]+=bfhi(sv.y);
  acc[4]+=bflo(sv.z); acc[5]+=bfhi(sv.z); acc[6]+=bflo(sv.w); acc[7]+=bfhi(sv.w);
  float dd = dinv[d];
  float val[8];
  #pragma unroll
  for(int k=0;k<8;k++){
    int col = li*8 + k;
    float bv = (col < FOUT) ? b2[col] : 0.f;
    val[k] = (col < FOUT) ? (acc[k]*dd + bv) : -3.402823466e38f;
  }
  float m = val[0];
  #pragma unroll
  for(int k=1;k<8;k++) m = fmaxf(m, val[k]);
  #pragma unroll
  for(int off=1; off<8; off<<=1) m = fmaxf(m, __shfl_xor(m, off));
  float ssum = 0.f;
  #pragma unroll
  for(int k=0;k<8;k++){
    int col = li*8 + k;
    ssum += (col < FOUT) ? expf(val[k] - m) : 0.f;
  }
  #pragma unroll
  for(int off=1; off<8; off<<=1) ssum += __shfl_xor(ssum, off);
  float lse = m + logf(ssum);
  if(g == 0 && li < 5){
    float4 o0 = {val[0]-lse, val[1]-lse, val[2]-lse, val[3]-lse};
    float4 o1 = {val[4]-lse, val[5]-lse, val[6]-lse, val[7]-lse};
    float* op = out + (size_t)d*FOUT + li*8;
    *(float4*)op = o0;
    *(float4*)(op+4) = o1;
  }
}

// ---------------- launch ----------------

extern "C" void kernel_launch(void* const* d_in, const int* in_sizes, int n_in,
                              void* d_out, int out_size, void* d_ws, size_t ws_size,
                              hipStream_t stream){
  const float* X  = (const float*)d_in[0];
  const int*   ei = (const int*)d_in[1];
  const float* W1 = (const float*)d_in[2];
  const float* b1 = (const float*)d_in[3];
  const float* W2 = (const float*)d_in[4];
  const float* b2 = (const float*)d_in[5];
  float* out = (float*)d_out;

  int n = in_sizes[0] / FIN;      // 100000
  int e = in_sizes[1] / 2;        // 1600000
  const int* src = ei;
  const int* dst = ei + e;

  // workspace layout
  ushort* XWs = (ushort*)d_ws;                       // n*128 bf16 (dinv-scaled XW)
  ushort* H1b = XWs + (size_t)n*FH;                  // n*128 bf16
  ushort* H2s = H1b + (size_t)n*FH;                  // n*64  bf16 (dinv-scaled, padded)
  ushort* W1t = H2s + (size_t)n*FP;                  // 128*512
  ushort* W2t = W1t + (size_t)FH*FIN;                // 48*128
  float* dinv = (float*)(W2t + 48*FH);               // n
  int* cnt    = (int*)(dinv + n);                    // n
  int* cursor = cnt + n;                             // n
  int* rp     = cursor + n;                          // n+1
  int* srcs   = rp + (n+1) + 3;                      // e
  int* aux    = srcs + e;                            // 256

  int nchunks = (n + 1023) / 1024;

  hipLaunchKernelGGL(k_zero_int, dim3((2*n+255)/256), dim3(256), 0, stream, cnt, 2*n);
  hipLaunchKernelGGL(k_count, dim3((e+255)/256), dim3(256), 0, stream, dst, e, cnt);
  hipLaunchKernelGGL(k_scan_a, dim3(nchunks), dim3(256), 0, stream, cnt, n, rp, aux);
  hipLaunchKernelGGL(k_scan_b, dim3(1), dim3(256), 0, stream, aux, nchunks);
  hipLaunchKernelGGL(k_scan_c, dim3((n+255)/256), dim3(256), 0, stream, rp, aux, cnt, dinv, n);
  hipLaunchKernelGGL(k_fill, dim3((e+255)/256), dim3(256), 0, stream, src, dst, e, rp, cursor, srcs);
  hipLaunchKernelGGL(k_prep, dim3((FIN*FH+255)/256), dim3(256), 0, stream, W1, W2, W1t, W2t);

  hipLaunchKernelGGL(k_gemm1_mfma, dim3((n+63)/64), dim3(256), 0, stream, X, W1t, dinv, XWs, n);
  hipLaunchKernelGGL(k_agg1, dim3((n+3)/4), dim3(256), 0, stream, XWs, rp, srcs, dinv, b1, H1b, n);
  hipLaunchKernelGGL(k_gemm2_mfma, dim3((n+127)/128), dim3(256), 0, stream, H1b, W2t, dinv, H2s, n);
  hipLaunchKernelGGL(k_agg2_sm, dim3((n+3)/4), dim3(256), 0, stream, H2s, rp, srcs, dinv, b2, out, n);
}

// Round 5
// 379.324 us; speedup vs baseline: 1.2821x; 1.2821x over previous
//
#include <hip/hip_runtime.h>
#include <math.h>

#define FIN 512
#define FH 128
#define FOUT 40
#define FP 64   // padded H2 width

typedef __attribute__((ext_vector_type(8))) short bf16x8;
typedef __attribute__((ext_vector_type(4))) float f32x4;

__device__ inline ushort f2bf(float f){
  union { float f; uint32_t u; } v; v.f = f;
  uint32_t u = v.u;
  uint32_t r = (u + 0x7FFF + ((u >> 16) & 1)) >> 16;
  return (ushort)r;
}
__device__ inline float bflo(uint32_t v){ union { uint32_t u; float f; } x; x.u = v << 16; return x.f; }
__device__ inline float bfhi(uint32_t v){ union { uint32_t u; float f; } x; x.u = v & 0xFFFF0000u; return x.f; }
__device__ inline uint32_t pk(float a, float b){ return (uint32_t)f2bf(a) | ((uint32_t)f2bf(b) << 16); }

// ---------------- CSR build ----------------

__global__ void k_zero_int(int* __restrict__ p, int n){
  int i = blockIdx.x*256 + threadIdx.x;
  if(i<n) p[i]=0;
}

__global__ void k_count(const int* __restrict__ dst, int e, int* __restrict__ cnt){
  int i = blockIdx.x*256 + threadIdx.x;
  if(i<e) atomicAdd(&cnt[dst[i]],1);
}

__global__ void k_scan_a(const int* __restrict__ cnt, int n, int* __restrict__ rp, int* __restrict__ aux){
  __shared__ int sh[256];
  int t = threadIdx.x;
  int base = blockIdx.x*1024;
  int v[4]; int s = 0;
  #pragma unroll
  for(int j=0;j<4;j++){ int idx = base + t*4 + j; int x = (idx<n)?cnt[idx]:0; v[j]=x; s+=x; }
  sh[t]=s; __syncthreads();
  for(int off=1; off<256; off<<=1){
    int x = (t>=off)? sh[t-off]:0; __syncthreads();
    sh[t]+=x; __syncthreads();
  }
  int run = (t>0)? sh[t-1]:0;
  #pragma unroll
  for(int j=0;j<4;j++){ run += v[j]; int idx = base + t*4 + j; if(idx<n) rp[idx+1]=run; }
  if(t==255) aux[blockIdx.x]=sh[255];
}

__global__ void k_scan_b(int* __restrict__ aux, int nchunks){
  __shared__ int sh[256];
  int t = threadIdx.x;
  sh[t] = (t<nchunks)? aux[t] : 0;
  __syncthreads();
  for(int off=1; off<256; off<<=1){
    int x = (t>=off)? sh[t-off]:0; __syncthreads();
    sh[t]+=x; __syncthreads();
  }
  if(t<nchunks) aux[t] = (t>0)? sh[t-1] : 0;
}

__global__ void k_scan_c(int* __restrict__ rp, const int* __restrict__ aux,
                         const int* __restrict__ cnt, float* __restrict__ dinv, int n){
  int i = blockIdx.x*256 + threadIdx.x;
  if(i<n){
    rp[i+1] += aux[i>>10];
    dinv[i] = rsqrtf((float)(cnt[i]+1));
  }
  if(i==0) rp[0] = 0;
}

__global__ void k_fill(const int* __restrict__ src, const int* __restrict__ dst, int e,
                       const int* __restrict__ rp, int* __restrict__ cursor, int* __restrict__ srcs){
  int i = blockIdx.x*256 + threadIdx.x;
  if(i<e){
    int d = dst[i];
    int p = rp[d] + atomicAdd(&cursor[d],1);
    srcs[p] = src[i];
  }
}

// ---------------- weight prep: W1 -> bf16 W1t[128][512]; W2 -> bf16 W2t[48][128] (pad 0) ---
__global__ void k_prep(const float* __restrict__ W1, const float* __restrict__ W2,
                       ushort* __restrict__ W1t, ushort* __restrict__ W2t){
  int i = blockIdx.x*256 + threadIdx.x;
  if(i < FIN*FH){
    int k = i / FH, c = i % FH;
    W1t[(size_t)c*FIN + k] = f2bf(W1[i]);
  }
  if(i < 48*FH){
    int c = i / FH, k = i % FH;
    W2t[i] = (c < FOUT) ? f2bf(W2[(size_t)k*FOUT + c]) : (ushort)0;
  }
}

// ---------------- GEMM1 via MFMA, W1 staged in LDS (two K-halves) ----------------
// 512 thr = 8 waves x 32 rows = 256 rows/block; B frags from swizzled LDS, A streamed.
__global__ __launch_bounds__(512, 4) void k_gemm1_mfma(const float* __restrict__ X,
                                                       const ushort* __restrict__ W1t,
                                                       const float* __restrict__ dinv,
                                                       ushort* __restrict__ XWs, int n){
  __shared__ ushort Ws[FH * 256];   // 64 KB: [128 cols][256 k] bf16, XOR-swizzled
  int t = threadIdx.x;
  int lane = t & 63;
  int wid = t >> 6;
  int l15 = lane & 15;
  int lk8 = (lane >> 4) * 8;
  int rowbase = blockIdx.x * 256 + wid * 32;

  int r0 = rowbase + l15;      if (r0 >= n) r0 = n-1;
  int r1 = rowbase + 16 + l15; if (r1 >= n) r1 = n-1;
  const float* a0p = X + (size_t)r0*FIN;
  const float* a1p = X + (size_t)r1*FIN;

  f32x4 acc[2][8];
  #pragma unroll
  for(int i=0;i<2;i++)
    #pragma unroll
    for(int j=0;j<8;j++) acc[i][j] = (f32x4){0.f,0.f,0.f,0.f};

  char* WsB = (char*)Ws;

  #pragma unroll
  for(int half=0; half<2; half++){
    if(half) __syncthreads();           // all waves done reading previous half
    // stage 64KB: 4096 x 16B chunks, 512 thr -> 8 iters
    #pragma unroll
    for(int it=0; it<8; it++){
      int c = it*512 + t;
      int col = c >> 5, kslot = c & 31;
      uint4 v = *(const uint4*)(W1t + (size_t)col*FIN + half*256 + kslot*8);
      int dstb = col*512 + ((kslot*16) ^ ((col & 7) << 4));
      *(uint4*)(WsB + dstb) = v;
    }
    __syncthreads();

    for(int kc=0; kc<8; kc++){
      int kl = kc*32 + lk8;             // local k within half
      int kg = half*256 + kl;           // global k
      float4 a0a = *(const float4*)(a0p + kg);
      float4 a0b = *(const float4*)(a0p + kg + 4);
      float4 a1a = *(const float4*)(a1p + kg);
      float4 a1b = *(const float4*)(a1p + kg + 4);
      bf16x8 fa0, fa1;
      fa0[0]=(short)f2bf(a0a.x); fa0[1]=(short)f2bf(a0a.y); fa0[2]=(short)f2bf(a0a.z); fa0[3]=(short)f2bf(a0a.w);
      fa0[4]=(short)f2bf(a0b.x); fa0[5]=(short)f2bf(a0b.y); fa0[6]=(short)f2bf(a0b.z); fa0[7]=(short)f2bf(a0b.w);
      fa1[0]=(short)f2bf(a1a.x); fa1[1]=(short)f2bf(a1a.y); fa1[2]=(short)f2bf(a1a.z); fa1[3]=(short)f2bf(a1a.w);
      fa1[4]=(short)f2bf(a1b.x); fa1[5]=(short)f2bf(a1b.y); fa1[6]=(short)f2bf(a1b.z); fa1[7]=(short)f2bf(a1b.w);

      #pragma unroll
      for(int fj=0; fj<8; fj++){
        int col = fj*16 + l15;
        int srcb = col*512 + ((kl*2) ^ ((col & 7) << 4));
        bf16x8 fb = *(const bf16x8*)(WsB + srcb);
        acc[0][fj] = __builtin_amdgcn_mfma_f32_16x16x32_bf16(fa0, fb, acc[0][fj], 0, 0, 0);
        acc[1][fj] = __builtin_amdgcn_mfma_f32_16x16x32_bf16(fa1, fb, acc[1][fj], 0, 0, 0);
      }
    }
  }

  int rbase = (lane >> 4) * 4;
  #pragma unroll
  for(int fi=0; fi<2; fi++){
    #pragma unroll
    for(int r=0; r<4; r++){
      int row = rowbase + fi*16 + rbase + r;
      if(row < n){
        float dd = dinv[row];
        #pragma unroll
        for(int fj=0; fj<8; fj++){
          XWs[(size_t)row*FH + fj*16 + l15] = f2bf(acc[fi][fj][r] * dd);
        }
      }
    }
  }
}

// ---------------- agg1: H1b = relu(dd*(sum_s XWs[s] + XWs[d]) + b1), bf16 out ----------------
// wave per node; 8 groups x 8 lanes; each group gathers a different edge row (2 x uint4 / lane).
__global__ __launch_bounds__(256) void k_agg1(const ushort* __restrict__ XWs, const int* __restrict__ rp,
                                              const int* __restrict__ srcs, const float* __restrict__ dinv,
                                              const float* __restrict__ b1, ushort* __restrict__ H1b, int n){
  int d = blockIdx.x*4 + (threadIdx.x >> 6);
  if(d >= n) return;
  int lane = threadIdx.x & 63;
  int g = lane >> 3, li = lane & 7;
  float acc[16];
  #pragma unroll
  for(int k=0;k<16;k++) acc[k]=0.f;
  int beg = rp[d], end = rp[d+1];
  for(int j = beg + g; j < end; j += 8){
    int s = srcs[j];
    const uint4* p = (const uint4*)(XWs + (size_t)s*FH + li*16);
    uint4 v0 = p[0];
    uint4 v1 = p[1];
    acc[0]+=bflo(v0.x); acc[1]+=bfhi(v0.x); acc[2]+=bflo(v0.y); acc[3]+=bfhi(v0.y);
    acc[4]+=bflo(v0.z); acc[5]+=bfhi(v0.z); acc[6]+=bflo(v0.w); acc[7]+=bfhi(v0.w);
    acc[8]+=bflo(v1.x); acc[9]+=bfhi(v1.x); acc[10]+=bflo(v1.y); acc[11]+=bfhi(v1.y);
    acc[12]+=bflo(v1.z); acc[13]+=bfhi(v1.z); acc[14]+=bflo(v1.w); acc[15]+=bfhi(v1.w);
  }
  #pragma unroll
  for(int k=0;k<16;k++){
    acc[k] += __shfl_xor(acc[k], 8);
    acc[k] += __shfl_xor(acc[k], 16);
    acc[k] += __shfl_xor(acc[k], 32);
  }
  // self + epilogue
  const uint4* sp = (const uint4*)(XWs + (size_t)d*FH + li*16);
  uint4 s0 = sp[0];
  uint4 s1 = sp[1];
  float dd = dinv[d];
  float slf[16];
  slf[0]=bflo(s0.x); slf[1]=bfhi(s0.x); slf[2]=bflo(s0.y); slf[3]=bfhi(s0.y);
  slf[4]=bflo(s0.z); slf[5]=bfhi(s0.z); slf[6]=bflo(s0.w); slf[7]=bfhi(s0.w);
  slf[8]=bflo(s1.x); slf[9]=bfhi(s1.x); slf[10]=bflo(s1.y); slf[11]=bfhi(s1.y);
  slf[12]=bflo(s1.z); slf[13]=bfhi(s1.z); slf[14]=bflo(s1.w); slf[15]=bfhi(s1.w);
  float o[16];
  #pragma unroll
  for(int k=0;k<16;k++){
    float bb = b1[li*16 + k];
    o[k] = fmaxf((acc[k]+slf[k])*dd + bb, 0.f);
  }
  if(g == 0){
    uint4 w0, w1;
    w0.x = pk(o[0],o[1]);  w0.y = pk(o[2],o[3]);  w0.z = pk(o[4],o[5]);  w0.w = pk(o[6],o[7]);
    w1.x = pk(o[8],o[9]);  w1.y = pk(o[10],o[11]); w1.z = pk(o[12],o[13]); w1.w = pk(o[14],o[15]);
    uint4* wp = (uint4*)(H1b + (size_t)d*FH + li*16);
    wp[0] = w0;
    wp[1] = w1;
  }
}

// ---------------- GEMM2 via MFMA: H2s[n,64] = (H1b @ W2) * dinv[row], bf16, cols>=40 zero ---
__global__ __launch_bounds__(256) void k_gemm2_mfma(const ushort* __restrict__ H1b,
                                                    const ushort* __restrict__ W2t,
                                                    const float* __restrict__ dinv,
                                                    ushort* __restrict__ H2s, int n){
  int t = threadIdx.x;
  int lane = t & 63;
  int wid = t >> 6;
  int l15 = lane & 15;
  int lk8 = (lane >> 4) * 8;
  int rowbase = blockIdx.x * 128 + wid * 32;

  int r0 = rowbase + l15;      if (r0 >= n) r0 = n-1;
  int r1 = rowbase + 16 + l15; if (r1 >= n) r1 = n-1;
  const ushort* a0p = H1b + (size_t)r0*FH + lk8;
  const ushort* a1p = H1b + (size_t)r1*FH + lk8;

  f32x4 acc[2][3];
  #pragma unroll
  for(int i=0;i<2;i++)
    #pragma unroll
    for(int j=0;j<3;j++) acc[i][j] = (f32x4){0.f,0.f,0.f,0.f};

  #pragma unroll
  for(int kc=0; kc<4; kc++){
    int k0 = kc*32;
    bf16x8 fa0 = *(const bf16x8*)(a0p + k0);
    bf16x8 fa1 = *(const bf16x8*)(a1p + k0);
    #pragma unroll
    for(int fj=0; fj<3; fj++){
      bf16x8 fb = *(const bf16x8*)(W2t + (size_t)(fj*16 + l15)*FH + k0 + lk8);
      acc[0][fj] = __builtin_amdgcn_mfma_f32_16x16x32_bf16(fa0, fb, acc[0][fj], 0, 0, 0);
      acc[1][fj] = __builtin_amdgcn_mfma_f32_16x16x32_bf16(fa1, fb, acc[1][fj], 0, 0, 0);
    }
  }

  int rbase = (lane >> 4) * 4;
  #pragma unroll
  for(int fi=0; fi<2; fi++){
    #pragma unroll
    for(int r=0; r<4; r++){
      int row = rowbase + fi*16 + rbase + r;
      if(row < n){
        float dd = dinv[row];
        #pragma unroll
        for(int fj=0; fj<3; fj++){
          int col = fj*16 + l15;
          H2s[(size_t)row*FP + col] = (col < FOUT) ? f2bf(acc[fi][fj][r] * dd) : (ushort)0;
        }
        H2s[(size_t)row*FP + 48 + l15] = 0;
      }
    }
  }
}

// ---------------- agg2 + bias + log_softmax: out[d] = lsm(dd*(sum H2s[s] + H2s[d]) + b2) ---
// wave per node; 8 groups x 8 lanes; 1 uint4/lane covers the 128B padded row.
__global__ __launch_bounds__(256) void k_agg2_sm(const ushort* __restrict__ H2s, const int* __restrict__ rp,
                                                 const int* __restrict__ srcs, const float* __restrict__ dinv,
                                                 const float* __restrict__ b2, float* __restrict__ out, int n){
  int d = blockIdx.x*4 + (threadIdx.x >> 6);
  if(d >= n) return;
  int lane = threadIdx.x & 63;
  int g = lane >> 3, li = lane & 7;
  float acc[8];
  #pragma unroll
  for(int k=0;k<8;k++) acc[k]=0.f;
  int beg = rp[d], end = rp[d+1];
  for(int j = beg + g; j < end; j += 8){
    int s = srcs[j];
    uint4 v = *(const uint4*)(H2s + (size_t)s*FP + li*8);
    acc[0]+=bflo(v.x); acc[1]+=bfhi(v.x); acc[2]+=bflo(v.y); acc[3]+=bfhi(v.y);
    acc[4]+=bflo(v.z); acc[5]+=bfhi(v.z); acc[6]+=bflo(v.w); acc[7]+=bfhi(v.w);
  }
  #pragma unroll
  for(int k=0;k<8;k++){
    acc[k] += __shfl_xor(acc[k], 8);
    acc[k] += __shfl_xor(acc[k], 16);
    acc[k] += __shfl_xor(acc[k], 32);
  }
  uint4 sv = *(const uint4*)(H2s + (size_t)d*FP + li*8);
  acc[0]+=bflo(sv.x); acc[1]+=bfhi(sv.x); acc[2]+=bflo(sv.y); acc[3]+=bfhi(sv.y);
  acc[4]+=bflo(sv.z); acc[5]+=bfhi(sv.z); acc[6]+=bflo(sv.w); acc[7]+=bfhi(sv.w);
  float dd = dinv[d];
  float val[8];
  #pragma unroll
  for(int k=0;k<8;k++){
    int col = li*8 + k;
    float bv = (col < FOUT) ? b2[col] : 0.f;
    val[k] = (col < FOUT) ? (acc[k]*dd + bv) : -3.402823466e38f;
  }
  float m = val[0];
  #pragma unroll
  for(int k=1;k<8;k++) m = fmaxf(m, val[k]);
  #pragma unroll
  for(int off=1; off<8; off<<=1) m = fmaxf(m, __shfl_xor(m, off));
  float ssum = 0.f;
  #pragma unroll
  for(int k=0;k<8;k++){
    int col = li*8 + k;
    ssum += (col < FOUT) ? expf(val[k] - m) : 0.f;
  }
  #pragma unroll
  for(int off=1; off<8; off<<=1) ssum += __shfl_xor(ssum, off);
  float lse = m + logf(ssum);
  if(g == 0 && li < 5){
    float4 o0 = {val[0]-lse, val[1]-lse, val[2]-lse, val[3]-lse};
    float4 o1 = {val[4]-lse, val[5]-lse, val[6]-lse, val[7]-lse};
    float* op = out + (size_t)d*FOUT + li*8;
    *(float4*)op = o0;
    *(float4*)(op+4) = o1;
  }
}

// ---------------- launch ----------------

extern "C" void kernel_launch(void* const* d_in, const int* in_sizes, int n_in,
                              void* d_out, int out_size, void* d_ws, size_t ws_size,
                              hipStream_t stream){
  const float* X  = (const float*)d_in[0];
  const int*   ei = (const int*)d_in[1];
  const float* W1 = (const float*)d_in[2];
  const float* b1 = (const float*)d_in[3];
  const float* W2 = (const float*)d_in[4];
  const float* b2 = (const float*)d_in[5];
  float* out = (float*)d_out;

  int n = in_sizes[0] / FIN;      // 100000
  int e = in_sizes[1] / 2;        // 1600000
  const int* src = ei;
  const int* dst = ei + e;

  // workspace layout
  ushort* XWs = (ushort*)d_ws;                       // n*128 bf16 (dinv-scaled XW)
  ushort* H1b = XWs + (size_t)n*FH;                  // n*128 bf16
  ushort* H2s = H1b + (size_t)n*FH;                  // n*64  bf16 (dinv-scaled, padded)
  ushort* W1t = H2s + (size_t)n*FP;                  // 128*512
  ushort* W2t = W1t + (size_t)FH*FIN;                // 48*128
  float* dinv = (float*)(W2t + 48*FH);               // n
  int* cnt    = (int*)(dinv + n);                    // n
  int* cursor = cnt + n;                             // n
  int* rp     = cursor + n;                          // n+1
  int* srcs   = rp + (n+1) + 3;                      // e
  int* aux    = srcs + e;                            // 256

  int nchunks = (n + 1023) / 1024;

  hipLaunchKernelGGL(k_zero_int, dim3((2*n+255)/256), dim3(256), 0, stream, cnt, 2*n);
  hipLaunchKernelGGL(k_count, dim3((e+255)/256), dim3(256), 0, stream, dst, e, cnt);
  hipLaunchKernelGGL(k_scan_a, dim3(nchunks), dim3(256), 0, stream, cnt, n, rp, aux);
  hipLaunchKernelGGL(k_scan_b, dim3(1), dim3(256), 0, stream, aux, nchunks);
  hipLaunchKernelGGL(k_scan_c, dim3((n+255)/256), dim3(256), 0, stream, rp, aux, cnt, dinv, n);
  hipLaunchKernelGGL(k_fill, dim3((e+255)/256), dim3(256), 0, stream, src, dst, e, rp, cursor, srcs);
  hipLaunchKernelGGL(k_prep, dim3((FIN*FH+255)/256), dim3(256), 0, stream, W1, W2, W1t, W2t);

  hipLaunchKernelGGL(k_gemm1_mfma, dim3((n+255)/256), dim3(512), 0, stream, X, W1t, dinv, XWs, n);
  hipLaunchKernelGGL(k_agg1, dim3((n+3)/4), dim3(256), 0, stream, XWs, rp, srcs, dinv, b1, H1b, n);
  hipLaunchKernelGGL(k_gemm2_mfma, dim3((n+127)/128), dim3(256), 0, stream, H1b, W2t, dinv, H2s, n);
  hipLaunchKernelGGL(k_agg2_sm, dim3((n+3)/4), dim3(256), 0, stream, H2s, rp, srcs, dinv, b2, out, n);
}